// Round 3
// baseline (329.082 us; speedup 1.0000x reference)
//
#include <hip/hip_runtime.h>
#include <hip/hip_bf16.h>
#include <stdint.h>

// Problem constants: B=2, L=512, D=1024, INNER=32, PAIR=128
// out[b,i,j,p] = sum_e q[b,j,e]*(k[b,i,e]*Wp[p,e] + Wd[p,e]) + (b_o[p] - sum_e k[b,i,e]*Wd[p,e])
//   => per (b,i): GEMM  G_i(128x32) x Q^T(32x512) (+ c0_i[p] on the m=p axis),
//      via mfma_f32_16x16x32_bf16 with A=G (m=p), B=q (n=j) so the accumulator's
//      4 regs/lane are CONSECUTIVE p -> direct dwordx4 stores, no LDS transpose.

typedef __attribute__((ext_vector_type(8))) short short8;
typedef __attribute__((ext_vector_type(4))) float floatx4;

__device__ __forceinline__ unsigned short f2bf(float f) {
    union { float f; unsigned int u; } v; v.f = f;
    return (unsigned short)((v.u + 0x7FFFu + ((v.u >> 16) & 1u)) >> 16); // RNE
}

__device__ __forceinline__ floatx4 fmadd4(float s, floatx4 w, floatx4 a) {
    a.x += s * w.x; a.y += s * w.y; a.z += s * w.z; a.w += s * w.w; return a;
}

// ---------------- k0: transpose weights ----------------
// Wt[d][o]  = W_proj[o][d]   (1024 x 64)   for coalesced k1 projection
// Wdt[e][p] = W_o[p][32+e]   (32 x 128)    for k1's c0 computation
__global__ __launch_bounds__(256) void k0_transpose(
    const float* __restrict__ Wproj, const float* __restrict__ Wo,
    float* __restrict__ Wt, float* __restrict__ Wdt)
{
    int g = blockIdx.x * 256 + threadIdx.x;
    if (g < 65536) {
        int o = g >> 10, d = g & 1023;
        Wt[d * 64 + o] = Wproj[g];
    } else {
        int h = g - 65536;           // 0..4095
        int p = h & 127, e = h >> 7; // e in [0,32)
        Wdt[e * 128 + p] = Wo[p * 64 + 32 + e];
    }
}

// ---------------- k1: LayerNorm + projection + c0 ----------------
// 256 blocks x 256 threads, 4 rows per block. Projection uses float4 Wt loads.
__global__ __launch_bounds__(256) void k1_ln_proj(
    const float* __restrict__ x, const float* __restrict__ gamma, const float* __restrict__ beta,
    const float* __restrict__ Wt, const float* __restrict__ b_proj,
    const float* __restrict__ Wdt, const float* __restrict__ b_o,
    unsigned short* __restrict__ Qbf, float* __restrict__ Kf, float* __restrict__ C0)
{
    __shared__ __attribute__((aligned(16))) float s_sh[4][1024];
    __shared__ __attribute__((aligned(16))) float part[4][16][68];  // [row][chunk][o]
    __shared__ float k_sh[4][32];

    const int t = threadIdx.x;
    const int w = t >> 6;        // wave id = local row for LN phase
    const int lane = t & 63;
    const int row = blockIdx.x * 4 + w;

    // --- LayerNorm of this wave's row ---
    const float* xr = x + (size_t)row * 1024;
    floatx4 xv[4];
    float sum = 0.f, sq = 0.f;
#pragma unroll
    for (int c = 0; c < 4; ++c) {
        xv[c] = *(const floatx4*)(xr + (c * 64 + lane) * 4);
        sum += xv[c].x + xv[c].y + xv[c].z + xv[c].w;
        sq  += xv[c].x * xv[c].x + xv[c].y * xv[c].y + xv[c].z * xv[c].z + xv[c].w * xv[c].w;
    }
#pragma unroll
    for (int m = 1; m < 64; m <<= 1) {
        sum += __shfl_xor(sum, m, 64);
        sq  += __shfl_xor(sq,  m, 64);
    }
    const float mu   = sum * (1.f / 1024.f);
    const float var  = sq * (1.f / 1024.f) - mu * mu;
    const float rsig = rsqrtf(var + 1e-5f);
#pragma unroll
    for (int c = 0; c < 4; ++c) {
        int d = (c * 64 + lane) * 4;
        floatx4 g4 = *(const floatx4*)(gamma + d);
        floatx4 b4 = *(const floatx4*)(beta + d);
        floatx4 s4;
        s4.x = (xv[c].x - mu) * rsig * g4.x + b4.x;
        s4.y = (xv[c].y - mu) * rsig * g4.y + b4.y;
        s4.z = (xv[c].z - mu) * rsig * g4.z + b4.z;
        s4.w = (xv[c].w - mu) * rsig * g4.w + b4.w;
        *(floatx4*)(&s_sh[w][d]) = s4;
    }
    __syncthreads();

    // --- projection: thread t -> outputs 4*(t&15)..+3, d-chunk (t>>4) of 64 ---
    {
        const int o4 = t & 15;
        const int ch = t >> 4;
        const floatx4* Wt4 = (const floatx4*)Wt;
        floatx4 a0 = {0.f, 0.f, 0.f, 0.f}, a1 = a0, a2 = a0, a3 = a0;
        const int dbase = ch * 64;
#pragma unroll 8
        for (int dd = 0; dd < 64; ++dd) {
            const int d = dbase + dd;
            floatx4 w4 = Wt4[d * 16 + o4];   // 16B coalesced, L2-resident
            a0 = fmadd4(s_sh[0][d], w4, a0);
            a1 = fmadd4(s_sh[1][d], w4, a1);
            a2 = fmadd4(s_sh[2][d], w4, a2);
            a3 = fmadd4(s_sh[3][d], w4, a3);
        }
        *(floatx4*)&part[0][ch][o4 * 4] = a0;
        *(floatx4*)&part[1][ch][o4 * 4] = a1;
        *(floatx4*)&part[2][ch][o4 * 4] = a2;
        *(floatx4*)&part[3][ch][o4 * 4] = a3;
    }
    __syncthreads();

    // --- combine partials: thread t -> (r = t>>6, o = t&63) ---
    {
        const int r = t >> 6, oo = t & 63;
        float v = b_proj[oo];
#pragma unroll
        for (int c = 0; c < 16; ++c) v += part[r][c][oo];
        const int rowr = blockIdx.x * 4 + r;
        if (oo < 32) {
            Qbf[rowr * 32 + oo] = f2bf(v);     // q in bf16 (MFMA B operand)
        } else {
            Kf[rowr * 32 + (oo - 32)] = v;     // k in fp32
            k_sh[r][oo - 32] = v;
        }
    }
    __syncthreads();

    // --- c0[row][p] = b_o[p] - sum_e k[row][e]*Wd[p][e]  (exact fp32) ---
    {
        const int p = t & 127;
        const int r0 = t >> 7;  // 0 or 1
#pragma unroll
        for (int rr = 0; rr < 2; ++rr) {
            const int r = r0 * 2 + rr;
            float a = 0.f;
#pragma unroll 8
            for (int e = 0; e < 32; ++e) a += k_sh[r][e] * Wdt[e * 128 + p];
            C0[(size_t)(blockIdx.x * 4 + r) * 128 + p] = b_o[p] - a;
        }
    }
}

// ---------------- k2: pairwise GEMM, transposed-operand form ----------------
// 2048 blocks x 256 threads: block = (bi, half of j). Per block: build
// Gt[p][e] (128x32 bf16) in LDS straight from W_o; A-frag = 8x ds_read_b128;
// C-init = floatx4 of c0 (varies along m=p); per j-tile: one 16B Qbf load,
// 8 MFMA, 8 direct nontemporal dwordx4 stores from acc regs. No LDS epilogue.
__global__ __launch_bounds__(256) void k2_pair(
    const unsigned short* __restrict__ Qbf, const float* __restrict__ Kf,
    const float* __restrict__ C0, const float* __restrict__ Wo,
    float* __restrict__ out)
{
    __shared__ __attribute__((aligned(16))) unsigned short Gt[128 * 32]; // [p][e]
    __shared__ __attribute__((aligned(16))) float c0s[128];
    __shared__ float ksh[32];

    const int t    = threadIdx.x;
    const int bi   = blockIdx.x >> 1;   // b*512 + i
    const int half = blockIdx.x & 1;
    const int b    = bi >> 9;

    if (t < 32)  ksh[t] = Kf[(size_t)bi * 32 + t];
    if (t < 128) c0s[t] = C0[(size_t)bi * 128 + t];
    __syncthreads();

    // Gt[p][e] = bf16( k_i[e]*Wp[p][e] + Wd[p][e] ) = bf16( ksh[e]*Wo[p][e] + Wo[p][32+e] )
#pragma unroll
    for (int it = 0; it < 16; ++it) {
        int idx = it * 256 + t;          // 0..4095
        int p = idx >> 5, e = idx & 31;
        float gv = ksh[e] * Wo[p * 64 + e] + Wo[p * 64 + 32 + e];
        Gt[p * 32 + e] = f2bf(gv);
    }
    __syncthreads();

    const int wave = t >> 6, lane = t & 63;
    const int col = lane & 15, quad = lane >> 4;

    // A fragments (m=p): a[u] = Gt[pt*16+col][quad*8+u]  -> one ds_read_b128 per pt
    short8 gfrag[8];
#pragma unroll
    for (int pt = 0; pt < 8; ++pt)
        gfrag[pt] = *(const short8*)&Gt[(pt * 16 + col) * 32 + quad * 8];

    // C-init: c0 varies along m=p: rows p = pt*16 + quad*4 + {0..3}
    floatx4 cinit[8];
#pragma unroll
    for (int pt = 0; pt < 8; ++pt)
        cinit[pt] = *(const floatx4*)&c0s[pt * 16 + quad * 4];

    const size_t outbase = (size_t)bi * (512 * 128);
    const unsigned short* qbase = Qbf + (size_t)b * 512 * 32;

    for (int l = 0; l < 4; ++l) {
        const int jt = half * 16 + wave * 4 + l;
        const int j0 = jt * 16;
        // B fragment (n=j): b[u] = q[j0+col][quad*8+u] -> one 16B load (L2-resident)
        const short8 qfrag = *(const short8*)(qbase + (size_t)(j0 + col) * 32 + quad * 8);
        floatx4 acc[8];
#pragma unroll
        for (int pt = 0; pt < 8; ++pt)
            acc[pt] = __builtin_amdgcn_mfma_f32_16x16x32_bf16(gfrag[pt], qfrag, cinit[pt], 0, 0, 0);
        // D[m=p][n=j]: lane holds p = pt*16+quad*4+{0..3} (consecutive!), j = j0+col.
        float* op = out + outbase + (size_t)(j0 + col) * 128 + quad * 4;
#pragma unroll
        for (int pt = 0; pt < 8; ++pt)
            __builtin_nontemporal_store(acc[pt], (floatx4*)(op + pt * 16));
    }
}

extern "C" void kernel_launch(void* const* d_in, const int* in_sizes, int n_in,
                              void* d_out, int out_size, void* d_ws, size_t ws_size,
                              hipStream_t stream) {
    const float* x     = (const float*)d_in[0];  // (2,512,1024)
    const float* gamma = (const float*)d_in[1];  // (1024)
    const float* beta  = (const float*)d_in[2];  // (1024)
    const float* Wproj = (const float*)d_in[3];  // (64,1024)
    const float* bproj = (const float*)d_in[4];  // (64)
    const float* Wo    = (const float*)d_in[5];  // (128,64)
    const float* bo    = (const float*)d_in[6];  // (128)
    float* out = (float*)d_out;                  // (2,512,512,128) fp32

    float* ws = (float*)d_ws;
    float* Wt  = ws;                    // 65536 floats (1024x64)
    float* Wdt = ws + 65536;            // 4096 floats  (32x128)
    float* Kf  = ws + 69632;            // 32768 floats (1024x32)
    float* C0  = ws + 102400;           // 131072 floats (1024x128)
    unsigned short* Qbf = (unsigned short*)(ws + 233472); // 32768 ushorts (1024x32)

    hipLaunchKernelGGL(k0_transpose, dim3(272), dim3(256), 0, stream,
                       Wproj, Wo, Wt, Wdt);
    hipLaunchKernelGGL(k1_ln_proj, dim3(256), dim3(256), 0, stream,
                       x, gamma, beta, Wt, bproj, Wdt, bo, Qbf, Kf, C0);
    hipLaunchKernelGGL(k2_pair, dim3(2048), dim3(256), 0, stream,
                       Qbf, Kf, C0, Wo, out);
}